// Round 1
// baseline (288.131 us; speedup 1.0000x reference)
//
#include <hip/hip_runtime.h>

typedef float f32x4 __attribute__((ext_vector_type(4)));
typedef short s16x8 __attribute__((ext_vector_type(8)));

// ---------- helpers ----------
__device__ __forceinline__ float us2f(unsigned short u) {
    union { unsigned int i; float f; } v;
    v.i = ((unsigned int)u) << 16;   // bf16 -> f32 exact
    return v.f;
}
__device__ __forceinline__ unsigned short f2us(float f) {
    union { unsigned int i; float f; } v; v.f = f;
    unsigned int r = v.i + 0x7fff + ((v.i >> 16) & 1);   // round-to-nearest-even
    return (unsigned short)(r >> 16);
}

// ================= K0: wprep (blocks 0..255) + hist (blocks 256..511) + last-block bscan ======
// bcnt/done zeroed by a preceding 2KB hipMemsetAsync.
__global__ __launch_bounds__(256) void k_prep_hist(const float* __restrict__ W1,
                                                   const float* __restrict__ W2,
                                                   const float* __restrict__ W3,
                                                   const float* __restrict__ Wc,
                                                   unsigned short* __restrict__ img,
                                                   const int* __restrict__ dst, int E, int chunk,
                                                   int* __restrict__ bcnt, int* __restrict__ done,
                                                   int* __restrict__ bofs, int* __restrict__ gcur) {
    __shared__ int cnt[256];
    __shared__ int lastflag;
    int t = threadIdx.x;
    if (blockIdx.x < 256) {
        // ---- weight prep: rows r = 2*blk + (t>>7), cols n = t&127 ----
        int r = (blockIdx.x << 1) | (t >> 7);
        int b = r >> 7, k = r & 127, n = t & 127;
        unsigned short *H, *L;
        float f;
        if (b < 3) {
            const float* W = (b == 0) ? W1 : ((b == 1) ? W2 : W3);
            H = img + b * 32768; L = H + 16384;
            f = W[k * 128 + n];
        } else {
            if (n >= 48) return;
            H = img + 3 * 32768; L = H + 6144;
            f = (n < 40) ? Wc[k * 40 + n] : 0.f;
        }
        unsigned short h = f2us(f);
        unsigned short l = f2us(f - us2f(h));
        int idx = n * 128 + ((((k >> 3) ^ (n & 15))) << 3) + (k & 7);
        H[idx] = h; L[idx] = l;
        return;
    }
    // ---- hist ----
    cnt[t] = 0; __syncthreads();
    int blk = blockIdx.x - 256;
    int s0 = blk * chunk;
    int s1 = s0 + chunk; if (s1 > E) s1 = E;
    for (int i = s0 + t; i < s1; i += 256) atomicAdd(&cnt[dst[i] >> 8], 1);
    __syncthreads();
    int c = cnt[t];
    if (c) atomicAdd(&bcnt[t], c);
    __syncthreads();
    if (t == 0) { __threadfence(); lastflag = (atomicAdd(done, 1) == 255); }
    __syncthreads();
    if (!lastflag) return;
    // ---- bscan (last hist block only) ----
    int v = __hip_atomic_load(&bcnt[t], __ATOMIC_RELAXED, __HIP_MEMORY_SCOPE_AGENT);
    cnt[t] = v; __syncthreads();
    for (int off = 1; off < 256; off <<= 1) {
        int x = (t >= off) ? cnt[t - off] : 0;
        __syncthreads();
        cnt[t] += x;
        __syncthreads();
    }
    int ex = cnt[t] - v;
    bofs[t] = ex; gcur[t] = ex;
    if (t == 255) bofs[256] = cnt[255];
}

// ================= MFMA GEMM core: M[i][c] = bf16((A@W)[i][c])  (no dinv — applied in gather)
template <bool ABF16>
__device__ __forceinline__ void gemm128_core(const void* __restrict__ Ap,
                                             const unsigned short* __restrict__ img,
                                             unsigned short* __restrict__ M, int N,
                                             int bid, int t,
                                             unsigned short* WsH, unsigned short* WsL) {
    {
        const uint4* s = (const uint4*)img;
        uint4* dH = (uint4*)WsH; uint4* dL = (uint4*)WsL;
#pragma unroll
        for (int i = 0; i < 8; i++) dH[t + i * 256] = s[t + i * 256];
#pragma unroll
        for (int i = 0; i < 8; i++) dL[t + i * 256] = s[2048 + t + i * 256];
    }
    __syncthreads();

    int w = t >> 6, lane = t & 63;
    int m = lane & 15, q = lane >> 4;
    int row0 = bid * 64 + w * 16;
    int gr = row0 + m;
    int grc = (gr < N) ? gr : (N - 1);
    const float* A32 = (const float*)Ap + (size_t)grc * 128;
    const unsigned short* A16 = (const unsigned short*)Ap + (size_t)grc * 128;
    int nbase = m * 128;

    f32x4 acc[8];
#pragma unroll
    for (int cb = 0; cb < 8; cb++) { acc[cb][0]=0.f; acc[cb][1]=0.f; acc[cb][2]=0.f; acc[cb][3]=0.f; }

#pragma unroll
    for (int ks = 0; ks < 4; ks++) {
        union { unsigned short u[8]; s16x8 v; } ah, al;
        if constexpr (ABF16) {
            ah.v = *(const s16x8*)&A16[ks * 32 + q * 8];
        } else {
            float4 f0 = ((const float4*)A32)[ks * 8 + q * 2];
            float4 f1 = ((const float4*)A32)[ks * 8 + q * 2 + 1];
            float fv[8] = {f0.x, f0.y, f0.z, f0.w, f1.x, f1.y, f1.z, f1.w};
#pragma unroll
            for (int j = 0; j < 8; j++) {
                unsigned short h = f2us(fv[j]);
                ah.u[j] = h;
                al.u[j] = f2us(fv[j] - us2f(h));
            }
        }
        int koff = (((ks * 4 + q) ^ m) & 15) << 3;
#pragma unroll
        for (int cb = 0; cb < 8; cb++) {
            int o = cb * 2048 + nbase + koff;
            s16x8 wh = *(const s16x8*)&WsH[o];
            s16x8 wl = *(const s16x8*)&WsL[o];
            acc[cb] = __builtin_amdgcn_mfma_f32_16x16x32_bf16(ah.v, wh, acc[cb], 0, 0, 0);
            acc[cb] = __builtin_amdgcn_mfma_f32_16x16x32_bf16(ah.v, wl, acc[cb], 0, 0, 0);
            if constexpr (!ABF16)
                acc[cb] = __builtin_amdgcn_mfma_f32_16x16x32_bf16(al.v, wh, acc[cb], 0, 0, 0);
        }
    }

#pragma unroll
    for (int r = 0; r < 4; r++) {
        int grow = row0 + q * 4 + r;
        if (grow < N) {
#pragma unroll
            for (int cb = 0; cb < 8; cb++)
                M[(size_t)grow * 128 + cb * 16 + m] = f2us(acc[cb][r]);
        }
    }
}

template <bool ABF16>
__global__ __launch_bounds__(256) void k_gemm128m(const void* __restrict__ Ap,
                                                  const unsigned short* __restrict__ img,
                                                  unsigned short* __restrict__ M, int N) {
    __shared__ __align__(16) unsigned short WsH[16384];
    __shared__ __align__(16) unsigned short WsL[16384];
    gemm128_core<ABF16>(Ap, img, M, N, blockIdx.x, threadIdx.x, WsH, WsL);
}

// ================= K1: scatter1 (blocks 0..255) || GEMM layer-1 (rest) =================
union KSM {
    struct { unsigned short H[16384]; unsigned short L[16384]; } w;
    int cnt[256];
};
__global__ __launch_bounds__(256) void k_sc1_gemm1(const int* __restrict__ src,
                                                   const int* __restrict__ dst, int E, int chunk,
                                                   int* __restrict__ gcur,
                                                   unsigned int* __restrict__ pk,
                                                   const float* __restrict__ x,
                                                   const unsigned short* __restrict__ img,
                                                   unsigned short* __restrict__ M, int N) {
    __shared__ __align__(16) KSM sm;
    int t = threadIdx.x;
    if (blockIdx.x < 256) {
        sm.cnt[t] = 0; __syncthreads();
        int s0 = blockIdx.x * chunk;
        int s1 = s0 + chunk; if (s1 > E) s1 = E;
        for (int i = s0 + t; i < s1; i += 256) atomicAdd(&sm.cnt[dst[i] >> 8], 1);
        __syncthreads();
        int base = atomicAdd(&gcur[t], sm.cnt[t]);
        sm.cnt[t] = base;
        __syncthreads();
        for (int i = s0 + t; i < s1; i += 256) {
            int d = dst[i];
            int slot = atomicAdd(&sm.cnt[d >> 8], 1);
            pk[slot] = ((unsigned int)src[i] << 8) | (unsigned int)(d & 255);
        }
        return;
    }
    gemm128_core<false>(x, img, M, N, blockIdx.x - 256, t, sm.w.H, sm.w.L);
}

// ================= K2: degscan + last-block scan2 + spin barrier + scatter2 ============
// 196 blocks < 256 CUs => all co-resident; flag3 spin is deadlock-free.
__global__ __launch_bounds__(256) void k_csr_finish(const unsigned int* __restrict__ pk,
                                                    const int* __restrict__ bofs,
                                                    int* __restrict__ row_ptr,
                                                    int* __restrict__ bsum,
                                                    float* __restrict__ dinv,
                                                    int* __restrict__ csr,
                                                    int N, int E, int nb,
                                                    int* __restrict__ done2,
                                                    int* __restrict__ flag3) {
    __shared__ int cnt[256];
    __shared__ int s[256];
    __shared__ int lastflag;
    int t = threadIdx.x, b = blockIdx.x;
    cnt[t] = 0; __syncthreads();
    int s0 = bofs[b], s1 = bofs[b + 1];
    for (int i = s0 + t; i < s1; i += 256) atomicAdd(&cnt[pk[i] & 255], 1);
    __syncthreads();
    int v = cnt[t];
    s[t] = v; __syncthreads();
    for (int off = 1; off < 256; off <<= 1) {
        int x = (t >= off) ? s[t - off] : 0;
        __syncthreads();
        s[t] += x;
        __syncthreads();
    }
    int node = (b << 8) + t;
    int rp_local = s[t] - v;                      // exclusive within bucket
    if (node < N) dinv[node] = rsqrtf((float)(v + 1));   // +1 self-loop
    if (t == 255) __hip_atomic_store(&bsum[b], s[255], __ATOMIC_RELAXED, __HIP_MEMORY_SCOPE_AGENT);
    __syncthreads();
    if (t == 0) { __threadfence(); lastflag = (atomicAdd(done2, 1) == nb - 1); }
    __syncthreads();
    if (lastflag) {
        // scan2 over bucket sums
        int vv = (t < nb) ? __hip_atomic_load(&bsum[t], __ATOMIC_RELAXED, __HIP_MEMORY_SCOPE_AGENT) : 0;
        s[t] = vv; __syncthreads();
        for (int off = 1; off < 256; off <<= 1) {
            int x = (t >= off) ? s[t - off] : 0;
            __syncthreads();
            s[t] += x;
            __syncthreads();
        }
        if (t < nb) __hip_atomic_store(&bsum[t], s[t] - vv, __ATOMIC_RELAXED, __HIP_MEMORY_SCOPE_AGENT);
        __syncthreads();
        if (t == 0) { __threadfence(); __hip_atomic_store(flag3, 1, __ATOMIC_RELEASE, __HIP_MEMORY_SCOPE_AGENT); }
    }
    if (t == 0) {
        while (__hip_atomic_load(flag3, __ATOMIC_ACQUIRE, __HIP_MEMORY_SCOPE_AGENT) == 0)
            __builtin_amdgcn_s_sleep(2);
    }
    __syncthreads();
    // scatter2
    int base = __hip_atomic_load(&bsum[b], __ATOMIC_RELAXED, __HIP_MEMORY_SCOPE_AGENT);
    int rp = 0;
    if (node < N) { rp = rp_local + base; row_ptr[node] = rp; }
    cnt[t] = rp;
    __syncthreads();
    for (int i = s0 + t; i < s1; i += 256) {
        unsigned int vpk = pk[i];
        int slot = atomicAdd(&cnt[vpk & 255], 1);
        csr[slot] = (int)(vpk >> 8);
    }
    if (node == N - 1) row_ptr[N] = E;
}

// ---------- gather: full 256 B rows, 4 rows/wave-instr; per-neighbor dinv fma ----------
template <bool OUT_BF16>
__global__ __launch_bounds__(256) void k_gather(const unsigned short* __restrict__ M,
                                                const int* __restrict__ csr,
                                                const int* __restrict__ row_ptr,
                                                const float* __restrict__ dinv,
                                                const float* __restrict__ bias,
                                                void* __restrict__ H, int N) {
    int w    = (blockIdx.x << 2) + (threadIdx.x >> 6);
    int lane = threadIdx.x & 63;
    if (w >= N) return;
    int g  = lane >> 4;      // neighbor group 0..3
    int sl = lane & 15;      // 16 B slot within row

    const uint4* M16 = (const uint4*)M;    // row = 16 uint4 (256 B)
    float dv = dinv[w];
    float acc[8];
#pragma unroll
    for (int i = 0; i < 8; i++) acc[i] = 0.f;

    auto accum = [&](uint4 tv, float sc) {
        unsigned int uu[4] = {tv.x, tv.y, tv.z, tv.w};
#pragma unroll
        for (int i = 0; i < 4; i++) {
            acc[2 * i]     = fmaf(sc, us2f((unsigned short)(uu[i] & 0xffffu)), acc[2 * i]);
            acc[2 * i + 1] = fmaf(sc, us2f((unsigned short)(uu[i] >> 16)), acc[2 * i + 1]);
        }
    };

    if (g == 0) accum(M16[(size_t)w * 16 + sl], dv);   // self term (once)

    int s0 = row_ptr[w], s1 = row_ptr[w + 1];
    for (int base = s0; base < s1; base += 64) {
        int n = s1 - base; if (n > 64) n = 64;
        int idx = (lane < n) ? csr[base + lane] : 0;
        int full = n >> 2;
        int rem  = n & 3;
        int j = 0;
        for (; j + 4 <= full; j += 4) {            // full-wave shfls
            int u0 = __shfl(idx, (j + 0) * 4 + g);
            int u1 = __shfl(idx, (j + 1) * 4 + g);
            int u2 = __shfl(idx, (j + 2) * 4 + g);
            int u3 = __shfl(idx, (j + 3) * 4 + g);
            float d0 = dinv[u0], d1 = dinv[u1], d2 = dinv[u2], d3 = dinv[u3];
            uint4 t0 = M16[(size_t)u0 * 16 + sl];
            uint4 t1 = M16[(size_t)u1 * 16 + sl];
            uint4 t2 = M16[(size_t)u2 * 16 + sl];
            uint4 t3 = M16[(size_t)u3 * 16 + sl];
            accum(t0, d0); accum(t1, d1); accum(t2, d2); accum(t3, d3);
        }
        for (; j < full; j++) {
            int u = __shfl(idx, j * 4 + g);
            accum(M16[(size_t)u * 16 + sl], dinv[u]);
        }
        int ur = __shfl(idx, ((full << 2) + g) & 63);   // full-wave
        if (g < rem) accum(M16[(size_t)ur * 16 + sl], dinv[ur]);
    }

    // reduce across the 4 groups
#pragma unroll
    for (int i = 0; i < 8; i++) {
        acc[i] += __shfl_xor(acc[i], 16);
        acc[i] += __shfl_xor(acc[i], 32);
    }

    const float4* b4 = (const float4*)bias;
    float4 b0 = b4[sl * 2], b1 = b4[sl * 2 + 1];
    float o[8];
    o[0] = fmaxf(fmaf(dv, acc[0], b0.x), 0.f);
    o[1] = fmaxf(fmaf(dv, acc[1], b0.y), 0.f);
    o[2] = fmaxf(fmaf(dv, acc[2], b0.z), 0.f);
    o[3] = fmaxf(fmaf(dv, acc[3], b0.w), 0.f);
    o[4] = fmaxf(fmaf(dv, acc[4], b1.x), 0.f);
    o[5] = fmaxf(fmaf(dv, acc[5], b1.y), 0.f);
    o[6] = fmaxf(fmaf(dv, acc[6], b1.z), 0.f);
    o[7] = fmaxf(fmaf(dv, acc[7], b1.w), 0.f);

    if (g == 0) {
        if constexpr (OUT_BF16) {
            uint4 p;
            p.x = (unsigned int)f2us(o[0]) | ((unsigned int)f2us(o[1]) << 16);
            p.y = (unsigned int)f2us(o[2]) | ((unsigned int)f2us(o[3]) << 16);
            p.z = (unsigned int)f2us(o[4]) | ((unsigned int)f2us(o[5]) << 16);
            p.w = (unsigned int)f2us(o[6]) | ((unsigned int)f2us(o[7]) << 16);
            ((uint4*)H)[(size_t)w * 16 + sl] = p;
        } else {
            float4* H4 = (float4*)H;
            H4[(size_t)w * 32 + sl * 2]     = make_float4(o[0], o[1], o[2], o[3]);
            H4[(size_t)w * 32 + sl * 2 + 1] = make_float4(o[4], o[5], o[6], o[7]);
        }
    }
}

// ================= MFMA classifier: out = h3 @ Wc + bc (cols padded to 48) =========
__global__ __launch_bounds__(256) void k_gemm40m(const float* __restrict__ A,
                                                 const unsigned short* __restrict__ img,
                                                 const float* __restrict__ bc,
                                                 float* __restrict__ out, int N) {
    __shared__ __align__(16) unsigned short WsH[6144];    // 12 KB
    __shared__ __align__(16) unsigned short WsL[6144];    // 12 KB
    int t = threadIdx.x;
    {
        const uint4* s = (const uint4*)img;
        uint4* dH = (uint4*)WsH; uint4* dL = (uint4*)WsL;
#pragma unroll
        for (int i = 0; i < 3; i++) dH[t + i * 256] = s[t + i * 256];
#pragma unroll
        for (int i = 0; i < 3; i++) dL[t + i * 256] = s[768 + t + i * 256];
    }
    __syncthreads();

    int w = t >> 6, lane = t & 63;
    int m = lane & 15, q = lane >> 4;
    int row0 = blockIdx.x * 64 + w * 16;
    int gr = row0 + m;
    int grc = (gr < N) ? gr : (N - 1);
    const float4* Arow = (const float4*)(A + (size_t)grc * 128);
    int nbase = m * 128;

    f32x4 acc[3];
#pragma unroll
    for (int cb = 0; cb < 3; cb++) { acc[cb][0]=0.f; acc[cb][1]=0.f; acc[cb][2]=0.f; acc[cb][3]=0.f; }

#pragma unroll
    for (int ks = 0; ks < 4; ks++) {
        float4 f0 = Arow[ks * 8 + q * 2];
        float4 f1 = Arow[ks * 8 + q * 2 + 1];
        float fv[8] = {f0.x, f0.y, f0.z, f0.w, f1.x, f1.y, f1.z, f1.w};
        union { unsigned short u[8]; s16x8 v; } ah, al;
#pragma unroll
        for (int j = 0; j < 8; j++) {
            unsigned short h = f2us(fv[j]);
            ah.u[j] = h;
            al.u[j] = f2us(fv[j] - us2f(h));
        }
        int koff = (((ks * 4 + q) ^ m) & 15) << 3;
#pragma unroll
        for (int cb = 0; cb < 3; cb++) {
            int o = cb * 2048 + nbase + koff;
            s16x8 wh = *(const s16x8*)&WsH[o];
            s16x8 wl = *(const s16x8*)&WsL[o];
            acc[cb] = __builtin_amdgcn_mfma_f32_16x16x32_bf16(ah.v, wh, acc[cb], 0, 0, 0);
            acc[cb] = __builtin_amdgcn_mfma_f32_16x16x32_bf16(ah.v, wl, acc[cb], 0, 0, 0);
            acc[cb] = __builtin_amdgcn_mfma_f32_16x16x32_bf16(al.v, wh, acc[cb], 0, 0, 0);
        }
    }

#pragma unroll
    for (int r = 0; r < 4; r++) {
        int grow = row0 + q * 4 + r;
        if (grow < N) {
#pragma unroll
            for (int cb = 0; cb < 3; cb++) {
                int col = cb * 16 + m;
                if (col < 40) out[(size_t)grow * 40 + col] = acc[cb][r] + bc[col];
            }
        }
    }
}

// ---------- launch ----------
extern "C" void kernel_launch(void* const* d_in, const int* in_sizes, int n_in,
                              void* d_out, int out_size, void* d_ws, size_t ws_size,
                              hipStream_t stream) {
    const float* x  = (const float*)d_in[0];
    const int*   ei = (const int*)d_in[1];
    const float* W1 = (const float*)d_in[2];
    const float* b1 = (const float*)d_in[3];
    const float* W2 = (const float*)d_in[4];
    const float* b2 = (const float*)d_in[5];
    const float* W3 = (const float*)d_in[6];
    const float* b3 = (const float*)d_in[7];
    const float* Wc = (const float*)d_in[8];
    const float* bc = (const float*)d_in[9];

    const int N = in_sizes[0] / 128;   // 50000
    const int E = in_sizes[1] / 2;     // 800000
    const int* src = ei;
    const int* dst = ei + E;

    // workspace carve-out (~33 MB)
    char* ws = (char*)d_ws;
    size_t off = 0;
    auto alloc = [&](size_t bytes) -> void* {
        void* p = ws + off;
        off = (off + bytes + 255) & ~(size_t)255;
        return p;
    };
    unsigned short* Mbuf = (unsigned short*)alloc((size_t)N * 128 * 2);  // bf16, row-major
    unsigned short* Hb   = (unsigned short*)alloc((size_t)N * 128 * 2);  // bf16 H (layers 1,2)
    unsigned int* pk     = (unsigned int*)alloc((size_t)E * 4);          // bucketed edges
    unsigned short* img  = (unsigned short*)alloc((3 * 32768 + 2 * 6144) * 2);
    float* dinv    = (float*)alloc((size_t)N * 4);
    int*   row_ptr = (int*)alloc((size_t)(N + 1) * 4);
    int*   csr     = (int*)alloc((size_t)E * 4);
    int*   ctrl    = (int*)alloc(512 * 4);    // [0..255]=bcnt, [256]=done, [257]=done2, [258]=flag3
    int*   bofs    = (int*)alloc(257 * 4);
    int*   gcur    = (int*)alloc(256 * 4);
    int*   bsum    = (int*)alloc(256 * 4);

    int* bcnt  = ctrl;
    int* done  = ctrl + 256;
    int* done2 = ctrl + 257;
    int* flag3 = ctrl + 258;

    float* out  = (float*)d_out;               // logits [N,40]
    float* hbuf = out + (size_t)N * 40;        // h3 region [N,128] fp32 (output)

    const int nb  = (N + 255) / 256;   // 196 (<=256)
    const int chunk = (E + 255) / 256;

    const int gb  = (N + 63) / 64;    // gemm blocks (BM=64)
    const int gab = (N + 3) / 4;      // gather blocks (4 waves/block)

    // zero control block (bcnt + done counters + spin flag)
    hipMemsetAsync(ctrl, 0, 512 * 4, stream);

    // K0: weight prep || edge histogram, last hist block scans buckets
    k_prep_hist<<<512, 256, 0, stream>>>(W1, W2, W3, Wc, img, dst, E, chunk,
                                         bcnt, done, bofs, gcur);
    // K1: scatter1 (blocks 0..255) || GEMM layer-1 (x fp32 -> Mbuf, no dinv)
    k_sc1_gemm1<<<256 + gb, 256, 0, stream>>>(src, dst, E, chunk, gcur, pk,
                                              x, img, Mbuf, N);
    // K2: per-bucket degree+scan, bucket-sum scan (last block), spin barrier, scatter2
    k_csr_finish<<<nb, 256, 0, stream>>>(pk, bofs, row_ptr, bsum, dinv, csr,
                                         N, E, nb, done2, flag3);

    // layer 1: Mbuf -> Hb(bf16)   (dinv applied per-neighbor in gather)
    k_gather<true><<<gab, 256, 0, stream>>>(Mbuf, csr, row_ptr, dinv, b1, Hb, N);
    // layer 2: Hb(bf16) -> M -> Hb
    k_gemm128m<true><<<gb, 256, 0, stream>>>(Hb, img + 32768, Mbuf, N);
    k_gather<true><<<gab, 256, 0, stream>>>(Mbuf, csr, row_ptr, dinv, b2, Hb, N);
    // layer 3: Hb(bf16) -> M -> h3(fp32, d_out)
    k_gemm128m<true><<<gb, 256, 0, stream>>>(Hb, img + 2 * 32768, Mbuf, N);
    k_gather<false><<<gab, 256, 0, stream>>>(Mbuf, csr, row_ptr, dinv, b3, hbuf, N);
    // classifier reads h3 fp32
    k_gemm40m<<<gb, 256, 0, stream>>>(hbuf, img + 3 * 32768, bc, out, N);
}